// Round 7
// baseline (1625.681 us; speedup 1.0000x reference)
//
#include <hip/hip_runtime.h>
#include <math.h>

typedef _Float16 f16;
typedef _Float16 f16x8 __attribute__((ext_vector_type(8)));
typedef float    f32x4 __attribute__((ext_vector_type(4)));

#define MFMA16(A, B, C) __builtin_amdgcn_mfma_f32_16x16x32_f16((A), (B), (C), 0, 0, 0)

// acc is pre-scaled: acc = -z (sigmoid gates) or -2z (tanh gate / cell).
__device__ __forceinline__ float sig_pre(float a) {
    return __builtin_amdgcn_rcpf(1.0f + __expf(a));
}

// B-fragment of W^T with scale s folded in: lane holds B[k0+j][n] = s*W[n][k0+j].
__device__ __forceinline__ f16x8 ldfrag(const float* __restrict__ W, int n, int k0, float s) {
    const float* p = W + (size_t)n * 64 + k0;
    f16x8 r;
#pragma unroll
    for (int j = 0; j < 8; j++) r[j] = (f16)(s * p[j]);
    return r;
}

// 512 threads = 8 waves = TWO independent batch-pairs (grp 0: waves 0-3,
// grp 1: waves 4-7) -> 2 waves/SIMD so stalls of one group hide under the
// other. Within a group: M=2 real MFMA rows (batch = row&1); wave wv owns
// gate columns n = g*64 + wv*16 + (lane&15); quads (0,2)=batch0, (1,3)=batch1.
__global__ __launch_bounds__(512, 2)
void seq2seq_kernel(const float* __restrict__ src, const float* __restrict__ trg,
                    const float* __restrict__ e1ih, const float* __restrict__ e1hh,
                    const float* __restrict__ e1b,
                    const float* __restrict__ e2ih, const float* __restrict__ e2hh,
                    const float* __restrict__ e2b,
                    const float* __restrict__ d1ih, const float* __restrict__ d1hh,
                    const float* __restrict__ d1b,
                    const float* __restrict__ d2ih, const float* __restrict__ d2hh,
                    const float* __restrict__ d2b,
                    const float* __restrict__ fcW, const float* __restrict__ fcb,
                    float* __restrict__ out)
{
    const int tid  = threadIdx.x;
    const int grp  = tid >> 8;               // which batch-pair group
    const int t2   = tid & 255;
    const int wv   = t2 >> 6;
    const int lane = tid & 63;               // real-wave lane (t2&63 == tid&63)
    const int quad = lane >> 4;
    const int c15  = lane & 15;
    const int u16  = wv * 16 + c15;          // hidden index this lane owns
    const int qb   = quad & 1;               // batch this lane processes
    const int ab   = c15 & 1;                // batch this lane's A-row feeds
    const int p    = 2 * blockIdx.x + grp;   // batch pair: batches 2p, 2p+1

    __shared__ __align__(16) f16 h1l[2][2][2][64];   // [grp][buf][bat][u]
    __shared__ __align__(16) f16 h2l[2][2][2][64];

    // ---- encoder weights: prescaled register-resident B-fragments ----
    f16x8 E1hh[4][2], E2ih[4][2], E2hh[4][2];
    float xw[4][3], bias1[4], bias2[4];
#pragma unroll
    for (int g = 0; g < 4; g++) {
        const float s = (g == 2) ? -2.0f : -1.0f;
        const int n = g * 64 + u16;
#pragma unroll
        for (int c = 0; c < 2; c++) {
            const int k0 = c * 32 + quad * 8;
            E1hh[g][c] = ldfrag(e1hh, n, k0, s);
            E2ih[g][c] = ldfrag(e2ih, n, k0, s);
            E2hh[g][c] = ldfrag(e2hh, n, k0, s);
        }
        xw[g][0] = s * e1ih[n * 3 + 0];
        xw[g][1] = s * e1ih[n * 3 + 1];
        xw[g][2] = s * e1ih[n * 3 + 2];
        bias1[g] = s * e1b[n];
        bias2[g] = s * e2b[n];
    }

    float c1 = 0.f, c2 = 0.f;                // state for (u16, qb)
    {
        f16* p1 = &h1l[grp][0][0][0];
        f16* p2 = &h2l[grp][0][0][0];
        p1[t2] = (f16)0.f;                   // 256 entries = 2*2*64 per group
        p2[t2] = (f16)0.f;
    }
    __syncthreads();

    const float* srow0 = src + (size_t)(2 * p) * 3072;
    const float* srow1 = src + (size_t)(2 * p + 1) * 3072;
    float x00 = srow0[0], x01 = srow0[1], x02 = srow0[2];
    float x10 = srow1[0], x11 = srow1[1], x12 = srow1[2];
    const f32x4 z4 = {0.f, 0.f, 0.f, 0.f};

    // ---------------- encoder: 1025 pipelined ticks, 1 barrier each --------
#pragma unroll 1
    for (int tau = 0; tau <= 1024; tau++) {
        const int w = tau & 1;
        const int tn = (tau + 1 < 1024) ? tau + 1 : 1023;
        float nx00 = srow0[tn * 3], nx01 = srow0[tn * 3 + 1], nx02 = srow0[tn * 3 + 2];
        float nx10 = srow1[tn * 3], nx11 = srow1[tn * 3 + 1], nx12 = srow1[tn * 3 + 2];

        const f16* h1p = h1l[grp][w ^ 1][ab];   // h1(tau-1), batch ab rows
        const f16* h2p = h2l[grp][w ^ 1][ab];   // h2(tau-2)
        f16x8 a0 = *(const f16x8*)(h1p + quad * 8);
        f16x8 a1 = *(const f16x8*)(h1p + 32 + quad * 8);
        f16x8 b0 = *(const f16x8*)(h2p + quad * 8);
        f16x8 b1 = *(const f16x8*)(h2p + 32 + quad * 8);

        const float xs0 = qb ? x10 : x00;
        const float xs1 = qb ? x11 : x01;
        const float xs2 = qb ? x12 : x02;

        if (tau < 1024) {                    // L1: h1(tau)
            f32x4 acc[4];
#pragma unroll
            for (int g = 0; g < 4; g++)
                acc[g] = MFMA16(a1, E1hh[g][1], MFMA16(a0, E1hh[g][0], z4));
            float v[4];
#pragma unroll
            for (int g = 0; g < 4; g++) {
                float av = qb ? acc[g][1] : acc[g][0];
                v[g] = av + fmaf(xw[g][0], xs0,
                            fmaf(xw[g][1], xs1, fmaf(xw[g][2], xs2, bias1[g])));
            }
            float iv = sig_pre(v[0]), fv = sig_pre(v[1]);
            float gv = 2.0f * sig_pre(v[2]) - 1.0f, ov = sig_pre(v[3]);
            c1 = fv * c1 + iv * gv;
            float th = 2.0f * sig_pre(-2.0f * c1) - 1.0f;
            if (quad < 2) h1l[grp][w][quad][u16] = (f16)(ov * th);
        }
        if (tau > 0) {                       // L2: h2(tau-1)
            f32x4 acc[4];
#pragma unroll
            for (int g = 0; g < 4; g++)
                acc[g] = MFMA16(b1, E2hh[g][1], MFMA16(b0, E2hh[g][0],
                         MFMA16(a1, E2ih[g][1], MFMA16(a0, E2ih[g][0], z4))));
            float v[4];
#pragma unroll
            for (int g = 0; g < 4; g++) {
                float av = qb ? acc[g][1] : acc[g][0];
                v[g] = av + bias2[g];
            }
            float iv = sig_pre(v[0]), fv = sig_pre(v[1]);
            float gv = 2.0f * sig_pre(v[2]) - 1.0f, ov = sig_pre(v[3]);
            c2 = fv * c2 + iv * gv;
            float th = 2.0f * sig_pre(-2.0f * c2) - 1.0f;
            if (quad < 2) h2l[grp][w][quad][u16] = (f16)(ov * th);
        }
        __syncthreads();                     // writes(w) visible; reads(w^1) done
        x00 = nx00; x01 = nx01; x02 = nx02;
        x10 = nx10; x11 = nx11; x12 = nx12;
    }
    // encoder final: h2(1023) in h2l[grp][0], c2 in regs

    // ---------------- decoder weights (reuse dead encoder registers) -------
    f16x8 D1hh[4][2], W2s[4][2];
    float dxw[4][3], db1[4], db2[4];
#pragma unroll
    for (int g = 0; g < 4; g++) {
        const float s = (g == 2) ? -2.0f : -1.0f;
        const int n = g * 64 + u16;
#pragma unroll
        for (int c = 0; c < 2; c++) {
            const int k0 = c * 32 + quad * 8;
            D1hh[g][c] = ldfrag(d1hh, n, k0, s);
            const float* pa = d2ih + (size_t)n * 64 + k0;
            const float* pb = d2hh + (size_t)n * 64 + k0;
            f16x8 r;
#pragma unroll
            for (int j = 0; j < 8; j++) r[j] = (f16)(s * (pa[j] + pb[j]));
            W2s[g][c] = r;
        }
        dxw[g][0] = s * d1ih[n * 3 + 0];
        dxw[g][1] = s * d1ih[n * 3 + 1];
        dxw[g][2] = s * d1ih[n * 3 + 2];
        db1[g] = s * d1b[n];
        db2[g] = s * d2b[n];
    }
    float fw0 = 0.f, fw1 = 0.f, fw2 = 0.f;
    float fb0 = fcb[0], fb1 = fcb[1], fb2 = fcb[2];
    if (wv < 2) { fw0 = fcW[lane]; fw1 = fcW[64 + lane]; fw2 = fcW[128 + lane]; }

    float cd = c2;
    const float* trow0 = trg + (size_t)(2 * p) * 1536;
    const float* trow1 = trg + (size_t)(2 * p + 1) * 1536;
    float t00 = trow0[0], t01 = trow0[1], t02 = trow0[2];
    float t10 = trow1[0], t11 = trow1[1], t12 = trow1[2];

    // ---------------- decoder: 511 steps, 2 barriers each ------------------
#pragma unroll 1
    for (int t = 0; t < 511; t++) {
        const int r = t & 1, w = r ^ 1;
        const int tn = (t + 1 < 511) ? t + 1 : 510;
        float n00 = trow0[tn * 3], n01 = trow0[tn * 3 + 1], n02 = trow0[tn * 3 + 2];
        float n10 = trow1[tn * 3], n11 = trow1[tn * 3 + 1], n12 = trow1[tn * 3 + 2];

        const f16* hp = h2l[grp][r][ab];     // hD(t-1)
        f16x8 a0 = *(const f16x8*)(hp + quad * 8);
        f16x8 a1 = *(const f16x8*)(hp + 32 + quad * 8);

        const float xs0 = qb ? t10 : t00;
        const float xs1 = qb ? t11 : t01;
        const float xs2 = qb ? t12 : t02;

        // dec1
        f32x4 acc[4];
#pragma unroll
        for (int g = 0; g < 4; g++)
            acc[g] = MFMA16(a1, D1hh[g][1], MFMA16(a0, D1hh[g][0], z4));
        float v[4];
#pragma unroll
        for (int g = 0; g < 4; g++) {
            float av = qb ? acc[g][1] : acc[g][0];
            v[g] = av + fmaf(dxw[g][0], xs0,
                        fmaf(dxw[g][1], xs1, fmaf(dxw[g][2], xs2, db1[g])));
        }
        float iv = sig_pre(v[0]), fv = sig_pre(v[1]);
        float gv = 2.0f * sig_pre(v[2]) - 1.0f, ov = sig_pre(v[3]);
        float c1d = fv * cd + iv * gv;
        float th1 = 2.0f * sig_pre(-2.0f * c1d) - 1.0f;
        if (quad < 2) h1l[grp][w][quad][u16] = (f16)(ov * th1);
        __syncthreads();   // B1: h1d visible

        // dec2: x = h = h1d -> summed (Wih2+Whh2)
        const f16* np = h1l[grp][w][ab];
        f16x8 m0 = *(const f16x8*)(np + quad * 8);
        f16x8 m1 = *(const f16x8*)(np + 32 + quad * 8);
#pragma unroll
        for (int g = 0; g < 4; g++)
            acc[g] = MFMA16(m1, W2s[g][1], MFMA16(m0, W2s[g][0], z4));
#pragma unroll
        for (int g = 0; g < 4; g++) {
            float av = qb ? acc[g][1] : acc[g][0];
            v[g] = av + db2[g];
        }
        float i2 = sig_pre(v[0]), f2 = sig_pre(v[1]);
        float g2 = 2.0f * sig_pre(v[2]) - 1.0f, o2 = sig_pre(v[3]);
        float c2d = f2 * c1d + i2 * g2;
        float th2 = 2.0f * sig_pre(-2.0f * c2d) - 1.0f;
        cd = c2d;
        if (quad < 2) h2l[grp][w][quad][u16] = (f16)(o2 * th2);
        __syncthreads();   // B2: hD(t) visible

        if (wv < 2) {      // FC head: wave wv of each group handles batch 2p+wv
            float hv = (float)h2l[grp][w][wv][lane];
            float p0 = fw0 * hv, p1 = fw1 * hv, p2 = fw2 * hv;
#pragma unroll
            for (int off = 32; off > 0; off >>= 1) {
                p0 += __shfl_down(p0, off);
                p1 += __shfl_down(p1, off);
                p2 += __shfl_down(p2, off);
            }
            if (lane == 0) {
                float* o = out + ((size_t)(2 * p + wv) * 512 + t + 1) * 3;
                o[0] = p0 + fb0; o[1] = p1 + fb1; o[2] = p2 + fb2;
            }
        }
        t00 = n00; t01 = n01; t02 = n02;
        t10 = n10; t11 = n11; t12 = n12;
    }
}

extern "C" void kernel_launch(void* const* d_in, const int* in_sizes, int n_in,
                              void* d_out, int out_size, void* d_ws, size_t ws_size,
                              hipStream_t stream)
{
    const float* src   = (const float*)d_in[0];
    const float* trg   = (const float*)d_in[1];
    const float* e1ih  = (const float*)d_in[2];
    const float* e1hh  = (const float*)d_in[3];
    const float* e1b   = (const float*)d_in[4];
    const float* e2ih  = (const float*)d_in[5];
    const float* e2hh  = (const float*)d_in[6];
    const float* e2b   = (const float*)d_in[7];
    const float* dd1ih = (const float*)d_in[8];
    const float* dd1hh = (const float*)d_in[9];
    const float* dd1b  = (const float*)d_in[10];
    const float* dd2ih = (const float*)d_in[11];
    const float* dd2hh = (const float*)d_in[12];
    const float* dd2b  = (const float*)d_in[13];
    const float* fcW   = (const float*)d_in[14];
    const float* fcb   = (const float*)d_in[15];
    float* out = (float*)d_out;

    // outputs[:, 0, :] stays 0; decoder fills t >= 1
    hipMemsetAsync(d_out, 0, (size_t)out_size * sizeof(float), stream);

    seq2seq_kernel<<<128, 512, 0, stream>>>(src, trg,
                                            e1ih, e1hh, e1b, e2ih, e2hh, e2b,
                                            dd1ih, dd1hh, dd1b, dd2ih, dd2hh, dd2b,
                                            fcW, fcb, out);
}

// Round 8
// 1049.012 us; speedup vs baseline: 1.5497x; 1.5497x over previous
//
#include <hip/hip_runtime.h>
#include <math.h>

typedef _Float16 f16;
typedef _Float16 f16x8 __attribute__((ext_vector_type(8)));
typedef float    f32x4 __attribute__((ext_vector_type(4)));

#define MFMA16(A, B, C) __builtin_amdgcn_mfma_f32_16x16x32_f16((A), (B), (C), 0, 0, 0)
#define LOG2E 1.44269504088896f

// Weights/biases are pre-scaled by -log2e (sigmoid gates) or -2*log2e (g gate),
// so sigma(z) = rcp(1 + 2^acc) with a bare v_exp_f32.
__device__ __forceinline__ float sig2(float a) {
    return __builtin_amdgcn_rcpf(1.0f + __builtin_amdgcn_exp2f(a));
}
// tanh(c) = 2*rcp(1+2^(-2*log2e*c)) - 1
__device__ __forceinline__ float tanh2(float c) {
    return fmaf(2.0f, sig2(c * (-2.0f * LOG2E)), -1.0f);
}

// B-fragment of W^T with scale s folded: lane holds B[k0+j][n] = s*W[n][k0+j].
__device__ __forceinline__ f16x8 ldfrag(const float* __restrict__ W, int n, int k0, float s) {
    const float* p = W + (size_t)n * 64 + k0;
    f16x8 r;
#pragma unroll
    for (int j = 0; j < 8; j++) r[j] = (f16)(s * p[j]);
    return r;
}

// One block per BATCH PAIR (M=2 real MFMA rows); 256 blocks (1/CU), 256 threads.
// Wave wv owns gate columns n = g*64 + wv*16 + (lane&15).
// A row m = batch (m&1) -> C: reg0 = batch0, reg1 = batch1; quads (0,2)=b0, (1,3)=b1.
__global__ __launch_bounds__(256, 2)
void seq2seq_kernel(const float* __restrict__ src, const float* __restrict__ trg,
                    const float* __restrict__ e1ih, const float* __restrict__ e1hh,
                    const float* __restrict__ e1b,
                    const float* __restrict__ e2ih, const float* __restrict__ e2hh,
                    const float* __restrict__ e2b,
                    const float* __restrict__ d1ih, const float* __restrict__ d1hh,
                    const float* __restrict__ d1b,
                    const float* __restrict__ d2ih, const float* __restrict__ d2hh,
                    const float* __restrict__ d2b,
                    const float* __restrict__ fcW, const float* __restrict__ fcb,
                    float* __restrict__ out)
{
    const int bp   = blockIdx.x;
    const int tid  = threadIdx.x;
    const int wv   = tid >> 6;
    const int lane = tid & 63;
    const int quad = lane >> 4;
    const int c15  = lane & 15;
    const int u16  = wv * 16 + c15;
    const int qb   = quad & 1;               // batch this lane processes
    const int ab   = c15 & 1;                // batch this lane's A-row feeds

    __shared__ __align__(16) float xst[1024][8];   // [t][bat*4+c] src, 32 KB
    __shared__ __align__(16) float tst[512][8];    // trg, 16 KB
    __shared__ __align__(16) f16 h1l[2][2][64];    // [buf][bat][u]
    __shared__ __align__(16) f16 h2l[2][2][64];

    // ---- one-time staging of src/trg into LDS (coalesced reads) ----
    {
        const float* s0 = src + (size_t)(2 * bp) * 3072;
        const float* s1 = s0 + 3072;
        for (int i = tid; i < 3072; i += 256) {
            int t = i / 3, c = i - 3 * t;
            xst[t][c]     = s0[i];
            xst[t][4 + c] = s1[i];
        }
        const float* t0p = trg + (size_t)(2 * bp) * 1536;
        const float* t1p = t0p + 1536;
        for (int i = tid; i < 1536; i += 256) {
            int t = i / 3, c = i - 3 * t;
            tst[t][c]     = t0p[i];
            tst[t][4 + c] = t1p[i];
        }
    }

    // ---- encoder weights: exp2-prescaled register-resident B-fragments ----
    f16x8 E1hh[4][2], E2ih[4][2], E2hh[4][2];
    float xw[4][3], bias1[4], bias2[4];
#pragma unroll
    for (int g = 0; g < 4; g++) {
        const float s = (g == 2) ? (-2.0f * LOG2E) : (-LOG2E);
        const int n = g * 64 + u16;
#pragma unroll
        for (int c = 0; c < 2; c++) {
            const int k0 = c * 32 + quad * 8;
            E1hh[g][c] = ldfrag(e1hh, n, k0, s);
            E2ih[g][c] = ldfrag(e2ih, n, k0, s);
            E2hh[g][c] = ldfrag(e2hh, n, k0, s);
        }
        xw[g][0] = s * e1ih[n * 3 + 0];
        xw[g][1] = s * e1ih[n * 3 + 1];
        xw[g][2] = s * e1ih[n * 3 + 2];
        bias1[g] = s * e1b[n];
        bias2[g] = s * e2b[n];
    }

    float c1 = 0.f, c2 = 0.f;                // cell state for (u16, qb)
    {
        f16* p1 = &h1l[0][0][0];
        f16* p2 = &h2l[0][0][0];
        p1[tid] = (f16)0.f;                  // 256 entries = 2*2*64
        p2[tid] = (f16)0.f;
    }
    __syncthreads();

    const f32x4 z4 = {0.f, 0.f, 0.f, 0.f};

    // ---------------- encoder: 1025 pipelined ticks, 1 barrier each --------
#pragma unroll 1
    for (int tau = 0; tau <= 1024; tau++) {
        const int w = tau & 1;
        const int tx = (tau < 1024) ? tau : 1023;
        const f32x4 xv = *(const f32x4*)&xst[tx][qb * 4];   // read-only region

        const f16* h1p = h1l[w ^ 1][ab];     // h1(tau-1), batch-ab rows
        const f16* h2p = h2l[w ^ 1][ab];     // h2(tau-2)
        f16x8 a0 = *(const f16x8*)(h1p + quad * 8);
        f16x8 a1 = *(const f16x8*)(h1p + 32 + quad * 8);
        f16x8 b0 = *(const f16x8*)(h2p + quad * 8);
        f16x8 b1 = *(const f16x8*)(h2p + 32 + quad * 8);

        // x-terms + bias, independent of h (off the post-MFMA path)
        float xt[4];
#pragma unroll
        for (int g = 0; g < 4; g++)
            xt[g] = fmaf(xw[g][0], xv.x,
                    fmaf(xw[g][1], xv.y, fmaf(xw[g][2], xv.z, bias1[g])));

        if (tau < 1024) {                    // L1: h1(tau)
            f32x4 acc[4];
#pragma unroll
            for (int g = 0; g < 4; g++)
                acc[g] = MFMA16(a1, E1hh[g][1], MFMA16(a0, E1hh[g][0], z4));
            float v[4];
#pragma unroll
            for (int g = 0; g < 4; g++)
                v[g] = (qb ? acc[g][1] : acc[g][0]) + xt[g];
            float iv = sig2(v[0]), fv = sig2(v[1]);
            float gv = fmaf(2.0f, sig2(v[2]), -1.0f), ov = sig2(v[3]);
            c1 = fv * c1 + iv * gv;
            if (quad < 2) h1l[w][quad][u16] = (f16)(ov * tanh2(c1));
        }
        if (tau > 0) {                       // L2: h2(tau-1)
            f32x4 acc[4];
#pragma unroll
            for (int g = 0; g < 4; g++)
                acc[g] = MFMA16(b1, E2hh[g][1], MFMA16(b0, E2hh[g][0],
                         MFMA16(a1, E2ih[g][1], MFMA16(a0, E2ih[g][0], z4))));
            float v[4];
#pragma unroll
            for (int g = 0; g < 4; g++)
                v[g] = (qb ? acc[g][1] : acc[g][0]) + bias2[g];
            float iv = sig2(v[0]), fv = sig2(v[1]);
            float gv = fmaf(2.0f, sig2(v[2]), -1.0f), ov = sig2(v[3]);
            c2 = fv * c2 + iv * gv;
            if (quad < 2) h2l[w][quad][u16] = (f16)(ov * tanh2(c2));
        }
        __syncthreads();                     // writes(w) visible; reads(w^1) done
    }
    // encoder final: h2(1023) in h2l[0], c2 in regs

    // ---------------- decoder weights (reuse dead encoder registers) -------
    f16x8 D1hh[4][2], W2s[4][2];
    float dxw[4][3], db1[4], db2[4];
#pragma unroll
    for (int g = 0; g < 4; g++) {
        const float s = (g == 2) ? (-2.0f * LOG2E) : (-LOG2E);
        const int n = g * 64 + u16;
#pragma unroll
        for (int c = 0; c < 2; c++) {
            const int k0 = c * 32 + quad * 8;
            D1hh[g][c] = ldfrag(d1hh, n, k0, s);
            const float* pa = d2ih + (size_t)n * 64 + k0;
            const float* pb = d2hh + (size_t)n * 64 + k0;
            f16x8 r;
#pragma unroll
            for (int j = 0; j < 8; j++) r[j] = (f16)(s * (pa[j] + pb[j]));
            W2s[g][c] = r;
        }
        dxw[g][0] = s * d1ih[n * 3 + 0];
        dxw[g][1] = s * d1ih[n * 3 + 1];
        dxw[g][2] = s * d1ih[n * 3 + 2];
        db1[g] = s * d1b[n];
        db2[g] = s * d2b[n];
    }
    float fw0 = 0.f, fw1 = 0.f, fw2 = 0.f;
    float fb0 = fcb[0], fb1 = fcb[1], fb2 = fcb[2];
    if (wv < 2) { fw0 = fcW[lane]; fw1 = fcW[64 + lane]; fw2 = fcW[128 + lane]; }

    float cd = c2;

    // ---------------- decoder: 511 steps, 2 barriers each ------------------
#pragma unroll 1
    for (int t = 0; t < 511; t++) {
        const int r = t & 1, w = r ^ 1;
        const f32x4 xv = *(const f32x4*)&tst[t][qb * 4];

        const f16* hp = h2l[r][ab];          // hD(t-1)
        f16x8 a0 = *(const f16x8*)(hp + quad * 8);
        f16x8 a1 = *(const f16x8*)(hp + 32 + quad * 8);

        float xt[4];
#pragma unroll
        for (int g = 0; g < 4; g++)
            xt[g] = fmaf(dxw[g][0], xv.x,
                    fmaf(dxw[g][1], xv.y, fmaf(dxw[g][2], xv.z, db1[g])));

        // dec1
        f32x4 acc[4];
#pragma unroll
        for (int g = 0; g < 4; g++)
            acc[g] = MFMA16(a1, D1hh[g][1], MFMA16(a0, D1hh[g][0], z4));
        float v[4];
#pragma unroll
        for (int g = 0; g < 4; g++)
            v[g] = (qb ? acc[g][1] : acc[g][0]) + xt[g];
        float iv = sig2(v[0]), fv = sig2(v[1]);
        float gv = fmaf(2.0f, sig2(v[2]), -1.0f), ov = sig2(v[3]);
        float c1d = fv * cd + iv * gv;
        if (quad < 2) h1l[w][quad][u16] = (f16)(ov * tanh2(c1d));
        __syncthreads();   // B1: h1d visible

        // dec2: x = h = h1d -> summed (Wih2+Whh2)
        const f16* np = h1l[w][ab];
        f16x8 m0 = *(const f16x8*)(np + quad * 8);
        f16x8 m1 = *(const f16x8*)(np + 32 + quad * 8);
#pragma unroll
        for (int g = 0; g < 4; g++)
            acc[g] = MFMA16(m1, W2s[g][1], MFMA16(m0, W2s[g][0], z4));
#pragma unroll
        for (int g = 0; g < 4; g++)
            v[g] = (qb ? acc[g][1] : acc[g][0]) + db2[g];
        float i2 = sig2(v[0]), f2 = sig2(v[1]);
        float g2 = fmaf(2.0f, sig2(v[2]), -1.0f), o2 = sig2(v[3]);
        float c2d = f2 * c1d + i2 * g2;
        cd = c2d;
        if (quad < 2) h2l[w][quad][u16] = (f16)(o2 * tanh2(c2d));
        __syncthreads();   // B2: hD(t) visible

        if (wv < 2) {      // FC head: wave wv handles batch wv
            float hv = (float)h2l[w][wv][lane];
            float p0 = fw0 * hv, p1 = fw1 * hv, p2 = fw2 * hv;
#pragma unroll
            for (int off = 32; off > 0; off >>= 1) {
                p0 += __shfl_down(p0, off);
                p1 += __shfl_down(p1, off);
                p2 += __shfl_down(p2, off);
            }
            if (lane == 0) {
                float* o = out + ((size_t)(2 * bp + wv) * 512 + t + 1) * 3;
                o[0] = p0 + fb0; o[1] = p1 + fb1; o[2] = p2 + fb2;
            }
        }
    }
}

extern "C" void kernel_launch(void* const* d_in, const int* in_sizes, int n_in,
                              void* d_out, int out_size, void* d_ws, size_t ws_size,
                              hipStream_t stream)
{
    const float* src   = (const float*)d_in[0];
    const float* trg   = (const float*)d_in[1];
    const float* e1ih  = (const float*)d_in[2];
    const float* e1hh  = (const float*)d_in[3];
    const float* e1b   = (const float*)d_in[4];
    const float* e2ih  = (const float*)d_in[5];
    const float* e2hh  = (const float*)d_in[6];
    const float* e2b   = (const float*)d_in[7];
    const float* dd1ih = (const float*)d_in[8];
    const float* dd1hh = (const float*)d_in[9];
    const float* dd1b  = (const float*)d_in[10];
    const float* dd2ih = (const float*)d_in[11];
    const float* dd2hh = (const float*)d_in[12];
    const float* dd2b  = (const float*)d_in[13];
    const float* fcW   = (const float*)d_in[14];
    const float* fcb   = (const float*)d_in[15];
    float* out = (float*)d_out;

    // outputs[:, 0, :] stays 0; decoder fills t >= 1
    hipMemsetAsync(d_out, 0, (size_t)out_size * sizeof(float), stream);

    seq2seq_kernel<<<256, 256, 0, stream>>>(src, trg,
                                            e1ih, e1hh, e1b, e2ih, e2hh, e2b,
                                            dd1ih, dd1hh, dd1b, dd2ih, dd2hh, dd2b,
                                            fcW, fcb, out);
}

// Round 9
// 925.961 us; speedup vs baseline: 1.7557x; 1.1329x over previous
//
#include <hip/hip_runtime.h>
#include <math.h>

typedef _Float16 f16;
typedef _Float16 f16x8 __attribute__((ext_vector_type(8)));
typedef float    f32x4 __attribute__((ext_vector_type(4)));

#define MFMA16(A, B, C) __builtin_amdgcn_mfma_f32_16x16x32_f16((A), (B), (C), 0, 0, 0)
#define LOG2E 1.44269504088896f

// Weights/biases pre-scaled by -log2e (sigmoid) or -2*log2e (g gate):
// sigma(z) = rcp(1 + 2^acc) with a bare v_exp_f32.
__device__ __forceinline__ float sig2(float a) {
    return __builtin_amdgcn_rcpf(1.0f + __builtin_amdgcn_exp2f(a));
}
__device__ __forceinline__ float tanh2(float c) {
    return fmaf(2.0f, sig2(c * (-2.0f * LOG2E)), -1.0f);
}

__device__ __forceinline__ f16x8 ldfrag(const float* __restrict__ W, int n, int k0, float s) {
    const float* p = W + (size_t)n * 64 + k0;
    f16x8 r;
#pragma unroll
    for (int j = 0; j < 8; j++) r[j] = (f16)(s * p[j]);
    return r;
}

// One block per BATCH PAIR; 512 threads = 8 waves, layer-specialized:
// waves 0-3 ("A") = encoder L1 / decoder dec1; waves 4-7 ("B") = encoder L2 /
// decoder dec2 (+ FC on waves 6-7, overlapped with next step's dec1 phase).
// Each SIMD hosts one A-wave and one B-wave -> 2 waves/SIMD hide each other's
// barrier/LDS/transcendental latency without raising per-SIMD issue load.
// M=2 MFMA rows: A-frag row m = batch m&1 -> C reg0=batch0, reg1=batch1;
// quads (0,2) process batch0 activations, (1,3) batch1.
__global__ __launch_bounds__(512, 2)
void seq2seq_kernel(const float* __restrict__ src, const float* __restrict__ trg,
                    const float* __restrict__ e1ih, const float* __restrict__ e1hh,
                    const float* __restrict__ e1b,
                    const float* __restrict__ e2ih, const float* __restrict__ e2hh,
                    const float* __restrict__ e2b,
                    const float* __restrict__ d1ih, const float* __restrict__ d1hh,
                    const float* __restrict__ d1b,
                    const float* __restrict__ d2ih, const float* __restrict__ d2hh,
                    const float* __restrict__ d2b,
                    const float* __restrict__ fcW, const float* __restrict__ fcb,
                    float* __restrict__ out)
{
    const int bp   = blockIdx.x;
    const int tid  = threadIdx.x;
    const int wv   = tid >> 6;               // 0..7
    const bool isB = (wv >= 4);
    const int wvg  = wv & 3;                 // wave index within group
    const int lane = tid & 63;
    const int quad = lane >> 4;
    const int c15  = lane & 15;
    const int u16  = wvg * 16 + c15;         // hidden index this lane owns
    const int qb   = quad & 1;               // batch this lane's activations
    const int ab   = c15 & 1;                // batch this lane's A-row feeds

    __shared__ __align__(16) float xst[1024][8];   // [t][bat*4+c] src, 32 KB
    __shared__ __align__(16) float tst[512][8];    // trg, 16 KB
    __shared__ __align__(16) f16 h1l[2][2][64];    // [buf][bat][u]
    __shared__ __align__(16) f16 h2l[2][2][64];
    __shared__ float c1buf[2][64];                 // dec1 cell out (A -> B)
    __shared__ float c2buf[2][64];                 // dec2 cell out (B -> A)

    // ---- one-time staging of src/trg into LDS ----
    {
        const float* s0 = src + (size_t)(2 * bp) * 3072;
        const float* s1 = s0 + 3072;
        for (int i = tid; i < 3072; i += 512) {
            int t = i / 3, c = i - 3 * t;
            xst[t][c]     = s0[i];
            xst[t][4 + c] = s1[i];
        }
        const float* t0p = trg + (size_t)(2 * bp) * 1536;
        const float* t1p = t0p + 1536;
        for (int i = tid; i < 1536; i += 512) {
            int t = i / 3, c = i - 3 * t;
            tst[t][c]     = t0p[i];
            tst[t][4 + c] = t1p[i];
        }
    }

    // ---- group-specialized encoder weights ----
    f16x8 E1hh[4][2];                        // A only
    f16x8 E2ih[4][2], E2hh[4][2];            // B only
    float xw[4][3], bias1[4], bias2[4];
    if (!isB) {
#pragma unroll
        for (int g = 0; g < 4; g++) {
            const float s = (g == 2) ? (-2.0f * LOG2E) : (-LOG2E);
            const int n = g * 64 + u16;
#pragma unroll
            for (int c = 0; c < 2; c++)
                E1hh[g][c] = ldfrag(e1hh, n, c * 32 + quad * 8, s);
            xw[g][0] = s * e1ih[n * 3 + 0];
            xw[g][1] = s * e1ih[n * 3 + 1];
            xw[g][2] = s * e1ih[n * 3 + 2];
            bias1[g] = s * e1b[n];
        }
    } else {
#pragma unroll
        for (int g = 0; g < 4; g++) {
            const float s = (g == 2) ? (-2.0f * LOG2E) : (-LOG2E);
            const int n = g * 64 + u16;
#pragma unroll
            for (int c = 0; c < 2; c++) {
                E2ih[g][c] = ldfrag(e2ih, n, c * 32 + quad * 8, s);
                E2hh[g][c] = ldfrag(e2hh, n, c * 32 + quad * 8, s);
            }
            bias2[g] = s * e2b[n];
        }
    }

    float c1 = 0.f, c2 = 0.f;                // c1 lives in A, c2 in B
    if (tid < 256) {
        (&h1l[0][0][0])[tid] = (f16)0.f;
        (&h2l[0][0][0])[tid] = (f16)0.f;
    }
    __syncthreads();

    const f32x4 z4 = {0.f, 0.f, 0.f, 0.f};

    // ---------------- encoder: 1025 pipelined ticks, 1 barrier each --------
#pragma unroll 1
    for (int tau = 0; tau <= 1024; tau++) {
        const int w = tau & 1;
        if (!isB) {
            if (tau < 1024) {                // L1: h1(tau) = f(h1(tau-1), x(tau))
                const f32x4 xv = *(const f32x4*)&xst[tau][qb * 4];
                const f16* h1p = h1l[w ^ 1][ab];
                f16x8 a0 = *(const f16x8*)(h1p + quad * 8);
                f16x8 a1 = *(const f16x8*)(h1p + 32 + quad * 8);
                float xt[4];
#pragma unroll
                for (int g = 0; g < 4; g++)
                    xt[g] = fmaf(xw[g][0], xv.x,
                            fmaf(xw[g][1], xv.y, fmaf(xw[g][2], xv.z, bias1[g])));
                f32x4 acc[4];
#pragma unroll
                for (int g = 0; g < 4; g++)
                    acc[g] = MFMA16(a1, E1hh[g][1], MFMA16(a0, E1hh[g][0], z4));
                float v[4];
#pragma unroll
                for (int g = 0; g < 4; g++)
                    v[g] = (qb ? acc[g][1] : acc[g][0]) + xt[g];
                float iv = sig2(v[0]), fv = sig2(v[1]);
                float gv = fmaf(2.0f, sig2(v[2]), -1.0f), ov = sig2(v[3]);
                c1 = fv * c1 + iv * gv;
                if (quad < 2) h1l[w][quad][u16] = (f16)(ov * tanh2(c1));
            }
        } else {
            if (tau > 0) {                   // L2: h2(tau-1) = f(h1(tau-1), h2(tau-2))
                const f16* h1p = h1l[w ^ 1][ab];
                const f16* h2p = h2l[w ^ 1][ab];
                f16x8 a0 = *(const f16x8*)(h1p + quad * 8);
                f16x8 a1 = *(const f16x8*)(h1p + 32 + quad * 8);
                f16x8 b0 = *(const f16x8*)(h2p + quad * 8);
                f16x8 b1 = *(const f16x8*)(h2p + 32 + quad * 8);
                f32x4 accA[4], accB[4];      // two 2-deep chains (shorter latency)
#pragma unroll
                for (int g = 0; g < 4; g++) {
                    accA[g] = MFMA16(a1, E2ih[g][1], MFMA16(a0, E2ih[g][0], z4));
                    accB[g] = MFMA16(b1, E2hh[g][1], MFMA16(b0, E2hh[g][0], z4));
                }
                float v[4];
#pragma unroll
                for (int g = 0; g < 4; g++)
                    v[g] = (qb ? accA[g][1] : accA[g][0]) +
                           (qb ? accB[g][1] : accB[g][0]) + bias2[g];
                float iv = sig2(v[0]), fv = sig2(v[1]);
                float gv = fmaf(2.0f, sig2(v[2]), -1.0f), ov = sig2(v[3]);
                c2 = fv * c2 + iv * gv;
                if (quad < 2) h2l[w][quad][u16] = (f16)(ov * tanh2(c2));
            }
        }
        __syncthreads();
    }
    // h2(1023) in h2l[0]; c2 in B registers

    // ---------------- decoder weights (group-specialized) -------------------
    f16x8 D1hh[4][2];                        // A
    f16x8 W2s[4][2];                         // B
    float dxw[4][3], db1[4], db2[4];
    if (!isB) {
#pragma unroll
        for (int g = 0; g < 4; g++) {
            const float s = (g == 2) ? (-2.0f * LOG2E) : (-LOG2E);
            const int n = g * 64 + u16;
#pragma unroll
            for (int c = 0; c < 2; c++)
                D1hh[g][c] = ldfrag(d1hh, n, c * 32 + quad * 8, s);
            dxw[g][0] = s * d1ih[n * 3 + 0];
            dxw[g][1] = s * d1ih[n * 3 + 1];
            dxw[g][2] = s * d1ih[n * 3 + 2];
            db1[g] = s * d1b[n];
        }
    } else {
#pragma unroll
        for (int g = 0; g < 4; g++) {
            const float s = (g == 2) ? (-2.0f * LOG2E) : (-LOG2E);
            const int n = g * 64 + u16;
#pragma unroll
            for (int c = 0; c < 2; c++) {
                const int k0 = c * 32 + quad * 8;
                const float* pa = d2ih + (size_t)n * 64 + k0;
                const float* pb = d2hh + (size_t)n * 64 + k0;
                f16x8 r;
#pragma unroll
                for (int j = 0; j < 8; j++) r[j] = (f16)(s * (pa[j] + pb[j]));
                W2s[g][c] = r;
            }
            db2[g] = s * d2b[n];
        }
        // seed c2buf with encoder final c2 (A reads it at t=0)
        if (quad < 2) c2buf[quad][u16] = c2;
    }
    float fw0 = 0.f, fw1 = 0.f, fw2 = 0.f;
    float fb0 = fcb[0], fb1 = fcb[1], fb2 = fcb[2];
    if (wv >= 6) { fw0 = fcW[lane]; fw1 = fcW[64 + lane]; fw2 = fcW[128 + lane]; }
    __syncthreads();

    // ---------------- decoder: 511 steps, 2 barriers each -------------------
#pragma unroll 1
    for (int t = 0; t < 511; t++) {
        const int r = t & 1, w = r ^ 1;
        if (!isB) {
            // ---- dec1 (waves 0-3) ----
            const f16* hp = h2l[r][ab];
            f16x8 a0 = *(const f16x8*)(hp + quad * 8);
            f16x8 a1 = *(const f16x8*)(hp + 32 + quad * 8);
            const f32x4 xv = *(const f32x4*)&tst[t][qb * 4];
            float cdin = c2buf[qb][u16];
            float xt[4];
#pragma unroll
            for (int g = 0; g < 4; g++)
                xt[g] = fmaf(dxw[g][0], xv.x,
                        fmaf(dxw[g][1], xv.y, fmaf(dxw[g][2], xv.z, db1[g])));
            f32x4 acc[4];
#pragma unroll
            for (int g = 0; g < 4; g++)
                acc[g] = MFMA16(a1, D1hh[g][1], MFMA16(a0, D1hh[g][0], z4));
            float v[4];
#pragma unroll
            for (int g = 0; g < 4; g++)
                v[g] = (qb ? acc[g][1] : acc[g][0]) + xt[g];
            float iv = sig2(v[0]), fv = sig2(v[1]);
            float gv = fmaf(2.0f, sig2(v[2]), -1.0f), ov = sig2(v[3]);
            float c1d = fv * cdin + iv * gv;
            if (quad < 2) {
                h1l[w][quad][u16] = (f16)(ov * tanh2(c1d));
                c1buf[quad][u16]  = c1d;
            }
        } else if (wv >= 6 && t > 0) {
            // ---- FC(t-1) on waves 6-7, overlapped with dec1 ----
            const int bsel = wv - 6;
            float hv = (float)h2l[r][bsel][lane];
            float p0 = fw0 * hv, p1 = fw1 * hv, p2 = fw2 * hv;
#pragma unroll
            for (int off = 32; off > 0; off >>= 1) {
                p0 += __shfl_down(p0, off);
                p1 += __shfl_down(p1, off);
                p2 += __shfl_down(p2, off);
            }
            if (lane == 0) {
                float* o = out + ((size_t)(2 * bp + bsel) * 512 + t) * 3;
                o[0] = p0 + fb0; o[1] = p1 + fb1; o[2] = p2 + fb2;
            }
        }
        __syncthreads();   // B1: h1d, c1d visible

        if (isB) {
            // ---- dec2 (waves 4-7): x = h = h1d ----
            const f16* np = h1l[w][ab];
            f16x8 m0 = *(const f16x8*)(np + quad * 8);
            f16x8 m1 = *(const f16x8*)(np + 32 + quad * 8);
            float c1in = c1buf[qb][u16];
            f32x4 acc[4];
#pragma unroll
            for (int g = 0; g < 4; g++)
                acc[g] = MFMA16(m1, W2s[g][1], MFMA16(m0, W2s[g][0], z4));
            float v[4];
#pragma unroll
            for (int g = 0; g < 4; g++)
                v[g] = (qb ? acc[g][1] : acc[g][0]) + db2[g];
            float i2 = sig2(v[0]), f2 = sig2(v[1]);
            float g2 = fmaf(2.0f, sig2(v[2]), -1.0f), o2 = sig2(v[3]);
            float c2d = f2 * c1in + i2 * g2;
            if (quad < 2) {
                h2l[w][quad][u16] = (f16)(o2 * tanh2(c2d));
                c2buf[quad][u16]  = c2d;
            }
        }
        __syncthreads();   // B2: hD(t), c2d visible
    }

    // final FC(510) -> out row 511 (h2l[1] written at step 510)
    if (wv >= 6) {
        const int bsel = wv - 6;
        float hv = (float)h2l[1][bsel][lane];
        float p0 = fw0 * hv, p1 = fw1 * hv, p2 = fw2 * hv;
#pragma unroll
        for (int off = 32; off > 0; off >>= 1) {
            p0 += __shfl_down(p0, off);
            p1 += __shfl_down(p1, off);
            p2 += __shfl_down(p2, off);
        }
        if (lane == 0) {
            float* o = out + ((size_t)(2 * bp + bsel) * 512 + 511) * 3;
            o[0] = p0 + fb0; o[1] = p1 + fb1; o[2] = p2 + fb2;
        }
    }
}

extern "C" void kernel_launch(void* const* d_in, const int* in_sizes, int n_in,
                              void* d_out, int out_size, void* d_ws, size_t ws_size,
                              hipStream_t stream)
{
    const float* src   = (const float*)d_in[0];
    const float* trg   = (const float*)d_in[1];
    const float* e1ih  = (const float*)d_in[2];
    const float* e1hh  = (const float*)d_in[3];
    const float* e1b   = (const float*)d_in[4];
    const float* e2ih  = (const float*)d_in[5];
    const float* e2hh  = (const float*)d_in[6];
    const float* e2b   = (const float*)d_in[7];
    const float* dd1ih = (const float*)d_in[8];
    const float* dd1hh = (const float*)d_in[9];
    const float* dd1b  = (const float*)d_in[10];
    const float* dd2ih = (const float*)d_in[11];
    const float* dd2hh = (const float*)d_in[12];
    const float* dd2b  = (const float*)d_in[13];
    const float* fcW   = (const float*)d_in[14];
    const float* fcb   = (const float*)d_in[15];
    float* out = (float*)d_out;

    // outputs[:, 0, :] stays 0; decoder fills t >= 1
    hipMemsetAsync(d_out, 0, (size_t)out_size * sizeof(float), stream);

    seq2seq_kernel<<<256, 512, 0, stream>>>(src, trg,
                                            e1ih, e1hh, e1b, e2ih, e2hh, e2b,
                                            dd1ih, dd1hh, dd1b, dd2ih, dd2hh, dd2b,
                                            fcW, fcb, out);
}